// Round 14
// baseline (218.894 us; speedup 1.0000x reference)
//
#include <hip/hip_runtime.h>

#define G_    1024
#define TPB   512
#define INF_F 3.4e38f

typedef __attribute__((ext_vector_type(8))) short short8;
typedef __attribute__((ext_vector_type(4))) float f32x4;

__device__ __forceinline__ float elu_fast(float x) { return x > 0.f ? x : __expf(x) - 1.f; }
__device__ __forceinline__ float elu_ref(float x)  { return x > 0.f ? x : expm1f(x); }

// Rotated row layouts (rotation multiple of 4 -> float4 stays aligned, 2-way banks)
#define ROT(r, d)    ((r)*128 + (((d) + 4*(r)) & 127))
#define BS1(s, c)    (2048 + (s)*128 + (((c) + 4*(s)) & 127))

#define FMA4(acc_, sc_, wv_) do { (acc_).x = fmaf((sc_),(wv_).x,(acc_).x); \
                                  (acc_).y = fmaf((sc_),(wv_).y,(acc_).y); \
                                  (acc_).z = fmaf((sc_),(wv_).z,(acc_).z); \
                                  (acc_).w = fmaf((sc_),(wv_).w,(acc_).w); } while(0)
#define MAX4(mm_, bb_)       do { (mm_).x = fmaxf((mm_).x,(bb_).x); \
                                  (mm_).y = fmaxf((mm_).y,(bb_).y); \
                                  (mm_).z = fmaxf((mm_).z,(bb_).z); \
                                  (mm_).w = fmaxf((mm_).w,(bb_).w); } while(0)

#define MFMA1(acc_, A_, B_) \
    acc_ = __builtin_amdgcn_mfma_f32_16x16x32_bf16((A_), (B_), (acc_), 0, 0, 0)

// SBAR between N-tile iterations: stops the scheduler from hoisting all 4 tiles'
// B loads + addresses above the MFMAs. R11 measured: without it WRITE_SIZE 153 MB
// of scratch spill; with it 61 MB. R13 (no SBAR) bounced back to 129 MB.
#define SBAR __builtin_amdgcn_sched_barrier(0)

union U8 { unsigned d[4]; short8 v; };

// RNE-pack 8 contiguous fp32 (two float4s) into one bf16 fragment (4 VGPRs).
// Single-plane: rel error ~2^-9; measured absmax 6e-6 end-to-end (R13) — no kNN flips.
__device__ __forceinline__ short8 pack_frag(const float* p0, const float* p1) {
    float xs[8];
    *(float4*)&xs[0] = *(const float4*)p0;
    *(float4*)&xs[4] = *(const float4*)p1;
    U8 uo;
    #pragma unroll
    for (int k = 0; k < 4; k++) {
        unsigned u0 = __float_as_uint(xs[2 * k]);
        unsigned u1 = __float_as_uint(xs[2 * k + 1]);
        u0 = u0 + 0x7FFFu + ((u0 >> 16) & 1u);   // round-to-nearest-even
        u1 = u1 + 0x7FFFu + ((u1 >> 16) & 1u);
        uo.d[k] = (u0 >> 16) | (u1 & 0xFFFF0000u);
    }
    return uo.v;
}

// prep: RNE bf16 single plane of 6 matrices, packed in B-fragment order.
// matrices: 0=W_trk2 1=W_sv2 2=Wc1_bot 3=Wd1 4=Wd2 5=Wc2_bot
__global__ void prep_pack(const float* __restrict__ Wtrk2, const float* __restrict__ Wsv2,
                          const float* __restrict__ Wc1,   const float* __restrict__ Wc2,
                          unsigned short* __restrict__ wsu) {
    const int o = blockIdx.x * 256 + threadIdx.x;
    if (o >= 6 * 16384) return;
    const int m = o >> 14, pos = o & 16383;
    const int j = pos & 7, lane = (pos >> 3) & 63, tile = pos >> 9;
    const int ks = tile >> 3, ni = tile & 7;
    const int d = ks * 32 + (lane >> 4) * 8 + j;
    const int c = ni * 16 + (lane & 15);
    const int e = d * 128 + c;
    float v;
    switch (m) {
        case 0: v = Wtrk2[e]; break;
        case 1: v = Wsv2[e]; break;
        case 2: v = Wc1[16384 + e]; break;
        case 3: v = Wc1[e] - Wc1[16384 + e]; break;
        case 4: v = Wc2[e] - Wc2[16384 + e]; break;
        default: v = Wc2[16384 + e]; break;
    }
    unsigned u = __float_as_uint(v);
    u = u + 0x7FFFu + ((u >> 16) & 1u);
    wsu[m * 16384 + pos] = (unsigned short)(u >> 16);
}

#define LOADB1(B_, m_, pos_) B_ = *(const short8*)(wsu + (m_) * 16384 + (pos_))

__global__ __launch_bounds__(TPB, 4)
void fused_mfma(const float* __restrict__ x_sv,  const float* __restrict__ x_trk,
                const float* __restrict__ W_sv1, const float* __restrict__ b_sv1,
                const float* __restrict__ b_sv2,
                const float* __restrict__ W_trk1,const float* __restrict__ b_trk1,
                const float* __restrict__ b_trk2,
                const float* __restrict__ b_c1,  const float* __restrict__ b_c2,
                const float* __restrict__ W_o1,  const float* __restrict__ b_o1,
                const float* __restrict__ W_o2,  const float* __restrict__ b_o2,
                const float* __restrict__ W_o3,  const float* __restrict__ b_o3,
                const float* __restrict__ W_o4,  const float* __restrict__ b_o4,
                const unsigned short* __restrict__ wsu,
                float* __restrict__ out)
{
    __shared__ float sA[8192];   // 32 KB : T (rot) -> bsrc2 (rot)
    __shared__ float sB[8192];   // 32 KB : h_trk/h_sv (rot) + svnorm -> scores1+packs -> f1 (rot) -> pool+head
    __shared__ float sC[4096];   // 16 KB : x stage + sv_emb (rot) + bsrc1 -> f1norm + scores2 + idx2
    unsigned* sBu = (unsigned*)sB;
    unsigned* sCu = (unsigned*)sC;

    const int g    = blockIdx.x;
    const int tid  = threadIdx.x;
    const int c128 = tid & 127;
    const int g4   = tid >> 7;
    const int wv   = tid >> 6;          // wave 0..7
    const int lane = tid & 63;
    const int quad = lane >> 4;
    const int ln   = lane & 15;

    // ---- P0: stage inputs
    sC[2048 + tid] = x_trk[(size_t)g * 512 + tid];
    if (tid < 32) sC[2560 + tid] = x_sv[(size_t)g * 32 + tid];
    __syncthreads();

    // ---- P1: trk MLP layer 1 -> h in sB (rot)
    {
        float w[8];
        #pragma unroll
        for (int k = 0; k < 8; k++) w[k] = W_trk1[k * 128 + c128];
        const float b1 = b_trk1[c128];
        #pragma unroll
        for (int i = 0; i < 16; i++) {
            const int r = g4 * 16 + i;
            float xr[8];
            *(float4*)&xr[0] = *(const float4*)&sC[2048 + r * 8];
            *(float4*)&xr[4] = *(const float4*)&sC[2048 + r * 8 + 4];
            float acc = b1;
            #pragma unroll
            for (int k = 0; k < 8; k++) acc = fmaf(xr[k], w[k], acc);
            sB[ROT(r, c128)] = elu_fast(acc);
        }
    }
    __syncthreads();

    // ---- P2 (MFMA): T = relu(h @ W_trk2 + b) -> sA (rot)
    {
        const int mi = wv >> 1, nb = (wv & 1) * 4;
        const int row = mi * 16 + ln;
        f32x4 acc[4];
        #pragma unroll
        for (int t = 0; t < 4; t++) {
            const float bz = b_trk2[(nb + t) * 16 + ln];
            acc[t] = (f32x4){bz, bz, bz, bz};
        }
        #pragma unroll
        for (int ks = 0; ks < 4; ks++) {
            const int k0 = ks * 32 + quad * 8;
            const short8 A = pack_frag(&sB[ROT(row, k0)], &sB[ROT(row, k0 + 4)]);
            #pragma unroll
            for (int t = 0; t < 4; t++) {
                SBAR;
                const int pos = ((ks * 8 + (nb + t)) * 64 + lane) * 8;
                short8 B;
                LOADB1(B, 0, pos);
                MFMA1(acc[t], A, B);
            }
        }
        #pragma unroll
        for (int t = 0; t < 4; t++)
            #pragma unroll
            for (int r = 0; r < 4; r++)
                sA[ROT(mi * 16 + quad * 4 + r, (nb + t) * 16 + ln)] = fmaxf(acc[t][r], 0.f);
    }
    __syncthreads();

    // ---- P3: sv MLP layer 1 -> h_sv rows 0..15 in sB (rot)
    {
        const float w0 = W_sv1[c128], w1 = W_sv1[128 + c128];
        const float b1 = b_sv1[c128];
        #pragma unroll
        for (int i = 0; i < 4; i++) {
            const int s = g4 * 4 + i;
            sB[ROT(s, c128)] =
                elu_fast(fmaf(sC[2560 + s * 2 + 1], w1, fmaf(sC[2560 + s * 2], w0, b1)));
        }
    }
    __syncthreads();

    // ---- P3b (MFMA): sv_emb -> sC rows 0..15 (rot); per-wave col-partial norms -> sB[2048+]
    {
        const int ni = wv;
        const float bz = b_sv2[ni * 16 + ln];
        f32x4 acc = (f32x4){bz, bz, bz, bz};
        #pragma unroll
        for (int ks = 0; ks < 4; ks++) {
            const int k0 = ks * 32 + quad * 8;
            const short8 A = pack_frag(&sB[ROT(ln, k0)], &sB[ROT(ln, k0 + 4)]);
            const int pos = ((ks * 8 + ni) * 64 + lane) * 8;
            short8 B;
            LOADB1(B, 1, pos);
            MFMA1(acc, A, B);
        }
        #pragma unroll
        for (int r = 0; r < 4; r++) {
            const float v = fmaxf(acc[r], 0.f);
            sC[ROT(quad * 4 + r, ni * 16 + ln)] = v;
            float p = v * v;
            #pragma unroll
            for (int o = 1; o <= 8; o <<= 1) p += __shfl_xor(p, o, 16);
            if (ln == 0) sB[2048 + ni * 16 + quad * 4 + r] = p;
        }
    }
    __syncthreads();

    // ---- B1 (MFMA): bsrc1 = sv @ Wc1_bot -> sC[2048..]; P4 (waves 0..3): scores1 -> sB
    {
        const int ni = wv;
        const bool doP4 = (wv < 4);
        f32x4 accB = (f32x4){0.f, 0.f, 0.f, 0.f};
        f32x4 accS = (f32x4){0.f, 0.f, 0.f, 0.f};
        #pragma unroll
        for (int ks = 0; ks < 4; ks++) {
            const int k0 = ks * 32 + quad * 8;
            const short8 S = pack_frag(&sC[ROT(ln, k0)], &sC[ROT(ln, k0 + 4)]);
            const int pos = ((ks * 8 + ni) * 64 + lane) * 8;
            short8 B;
            LOADB1(B, 2, pos);
            MFMA1(accB, S, B);
            if (doP4) {
                const int row = wv * 16 + ln;   // T row (mi = wv)
                const short8 T = pack_frag(&sA[ROT(row, k0)], &sA[ROT(row, k0 + 4)]);
                MFMA1(accS, T, S);
            }
        }
        #pragma unroll
        for (int r = 0; r < 4; r++)
            sC[BS1(quad * 4 + r, ni * 16 + ln)] = accB[r];
        if (doP4) {
            float nsv = 0.f;
            #pragma unroll
            for (int p = 0; p < 8; p++) nsv += sB[2048 + p * 16 + ln];
            #pragma unroll
            for (int r = 0; r < 4; r++)
                sB[(wv * 16 + quad * 4 + r) * 17 + ln] = fmaf(-2.f, accS[r], nsv);
        }
    }
    __syncthreads();

    // ---- topk1: top-8 of 16 (shfl) -> packs sBu[1088+q]
    {
        const int q  = tid >> 3;
        const int s0 = tid & 7;
        float sc0 = sB[q * 17 + s0];
        float sc1 = sB[q * 17 + s0 + 8];
        unsigned pack1 = 0u;
        #pragma unroll
        for (int r = 0; r < 8; r++) {
            float bv = sc0; int bs = s0;
            if (sc1 < bv) { bv = sc1; bs = s0 + 8; }
            #pragma unroll
            for (int o = 1; o <= 4; o <<= 1) {
                const float ov = __shfl_xor(bv, o, 8);
                const int   os = __shfl_xor(bs, o, 8);
                if (ov < bv || (ov == bv && os < bs)) { bv = ov; bs = os; }
            }
            pack1 |= (unsigned)bs << (4 * r);
            if (bs == s0)     sc0 = INF_F;
            if (bs == s0 + 8) sc1 = INF_F;
        }
        if (s0 == 0) sBu[1088 + q] = pack1;
    }
    __syncthreads();

    // ---- Phase6 (MFMA, fused a1+a2 in one A pass): a1,a2 = T @ Wd1/Wd2 + b ;
    //      f1 = elu(a1 + max bsrc1[idx]) -> sB ; f1-norms -> sC[0..127]
    f32x4 a2acc[4];
    {
        const int mi = wv >> 1, nb = (wv & 1) * 4;
        const int row = mi * 16 + ln;
        f32x4 a1acc[4];
        #pragma unroll
        for (int t = 0; t < 4; t++) {
            const float bz1 = b_c1[(nb + t) * 16 + ln];
            const float bz2 = b_c2[(nb + t) * 16 + ln];
            a1acc[t] = (f32x4){bz1, bz1, bz1, bz1};
            a2acc[t] = (f32x4){bz2, bz2, bz2, bz2};
        }
        #pragma unroll
        for (int ks = 0; ks < 4; ks++) {
            const int k0 = ks * 32 + quad * 8;
            const short8 A = pack_frag(&sA[ROT(row, k0)], &sA[ROT(row, k0 + 4)]);
            #pragma unroll
            for (int t = 0; t < 4; t++) {
                SBAR;
                const int pos = ((ks * 8 + (nb + t)) * 64 + lane) * 8;
                short8 B;
                LOADB1(B, 3, pos);
                MFMA1(a1acc[t], A, B);
                LOADB1(B, 4, pos);
                MFMA1(a2acc[t], A, B);
            }
        }
        // read packs into regs BEFORE barrier (f1 writes below overwrite sB row 8,
        // which aliases sBu[1088..1151])
        unsigned pk[4];
        #pragma unroll
        for (int r = 0; r < 4; r++) pk[r] = sBu[1088 + mi * 16 + quad * 4 + r];
        __syncthreads();
        float np[4] = {0.f, 0.f, 0.f, 0.f};
        #pragma unroll
        for (int t = 0; t < 4; t++) {
            const int cc = (nb + t) * 16 + ln;
            #pragma unroll
            for (int r = 0; r < 4; r++) {
                float mx = -INF_F;
                #pragma unroll
                for (int j = 0; j < 8; j++) {
                    const int s = (int)((pk[r] >> (4 * j)) & 15u);
                    mx = fmaxf(mx, sC[BS1(s, cc)]);
                }
                const float f = elu_fast(a1acc[t][r] + mx);
                sB[ROT(mi * 16 + quad * 4 + r, cc)] = f;
                np[r] = fmaf(f, f, np[r]);
            }
        }
        #pragma unroll
        for (int r = 0; r < 4; r++) {
            #pragma unroll
            for (int o = 1; o <= 8; o <<= 1) np[r] += __shfl_xor(np[r], o, 16);
            if (ln == 0) sC[(wv & 1) * 64 + mi * 16 + quad * 4 + r] = np[r];
        }
    }
    __syncthreads();

    // ---- Phase7 (MFMA): scores2[q][s] = n_s - 2 T_q . f1_s -> sC[q*64+s]
    {
        const int mi = wv >> 1, nia = (wv & 1) * 2;
        const int row = mi * 16 + ln;
        float ns[2];
        #pragma unroll
        for (int u = 0; u < 2; u++) {
            const int s = (nia + u) * 16 + ln;
            ns[u] = sC[s] + sC[64 + s];
        }
        __syncthreads();   // norms read before scores overwrite sC
        f32x4 acc[2];
        acc[0] = (f32x4){0.f, 0.f, 0.f, 0.f};
        acc[1] = (f32x4){0.f, 0.f, 0.f, 0.f};
        #pragma unroll
        for (int ks = 0; ks < 4; ks++) {
            const int k0 = ks * 32 + quad * 8;
            const short8 A = pack_frag(&sA[ROT(row, k0)], &sA[ROT(row, k0 + 4)]);
            #pragma unroll
            for (int u = 0; u < 2; u++) {
                SBAR;
                const int srow = (nia + u) * 16 + ln;
                const short8 B = pack_frag(&sB[ROT(srow, k0)], &sB[ROT(srow, k0 + 4)]);
                MFMA1(acc[u], A, B);
            }
        }
        #pragma unroll
        for (int u = 0; u < 2; u++) {
            const int s = (nia + u) * 16 + ln;
            #pragma unroll
            for (int r = 0; r < 4; r++)
                sC[(mi * 16 + quad * 4 + r) * 64 + s] = fmaf(-2.f, acc[u][r], ns[u]);
        }
    }
    __syncthreads();

    // ---- topk2: top-8 of 64 (shfl)
    unsigned lo2, hi2;
    {
        const int q = tid >> 3;
        const int j = tid & 7;
        float v[8];
        *(float4*)&v[0] = *(const float4*)&sC[q * 64 + 8 * j];
        *(float4*)&v[4] = *(const float4*)&sC[q * 64 + 8 * j + 4];
        lo2 = 0u; hi2 = 0u;
        #pragma unroll
        for (int r = 0; r < 8; r++) {
            float bv = v[0]; int bs = 8 * j;
            #pragma unroll
            for (int t = 1; t < 8; t++)
                if (v[t] < bv) { bv = v[t]; bs = 8 * j + t; }
            #pragma unroll
            for (int o = 1; o <= 4; o <<= 1) {
                const float ov = __shfl_xor(bv, o, 8);
                const int   os = __shfl_xor(bs, o, 8);
                if (ov < bv || (ov == bv && os < bs)) { bv = ov; bs = os; }
            }
            if (r < 4) lo2 |= (unsigned)bs << (8 * r);
            else       hi2 |= (unsigned)bs << (8 * (r - 4));
            #pragma unroll
            for (int t = 0; t < 8; t++)
                if (bs == 8 * j + t) v[t] = INF_F;
        }
    }
    __syncthreads();

    // ---- idx2 handoff + P8d (MFMA): bsrc2 = f1 @ Wc2_bot -> sA (T dead: a2 already done)
    if ((tid & 7) == 0) {
        const int q = tid >> 3;
        sCu[2 * q]     = lo2;
        sCu[2 * q + 1] = hi2;
    }
    {
        const int mi = wv >> 1, nb = (wv & 1) * 4;
        const int row = mi * 16 + ln;
        f32x4 acc[4];
        #pragma unroll
        for (int t = 0; t < 4; t++) acc[t] = (f32x4){0.f, 0.f, 0.f, 0.f};
        #pragma unroll
        for (int ks = 0; ks < 4; ks++) {
            const int k0 = ks * 32 + quad * 8;
            const short8 A = pack_frag(&sB[ROT(row, k0)], &sB[ROT(row, k0 + 4)]);
            #pragma unroll
            for (int t = 0; t < 4; t++) {
                SBAR;
                const int pos = ((ks * 8 + (nb + t)) * 64 + lane) * 8;
                short8 B;
                LOADB1(B, 5, pos);
                MFMA1(acc[t], A, B);
            }
        }
        #pragma unroll
        for (int t = 0; t < 4; t++)
            #pragma unroll
            for (int r = 0; r < 4; r++)
                sA[ROT(mi * 16 + quad * 4 + r, (nb + t) * 16 + ln)] = acc[t][r];
    }
    __syncthreads();

    // ---- Phase9: f2 = elu(a2 + max bsrc2[idx]) ; pool -> sB[0..511]
    {
        const int mi = wv >> 1, nb = (wv & 1) * 4;
        float ps[4] = {0.f, 0.f, 0.f, 0.f};
        #pragma unroll
        for (int t = 0; t < 4; t++) {
            const int cc = (nb + t) * 16 + ln;
            #pragma unroll
            for (int r = 0; r < 4; r++) {
                const int rr = mi * 16 + quad * 4 + r;
                const unsigned plo = sCu[2 * rr];
                const unsigned phi = sCu[2 * rr + 1];
                float mx = -INF_F;
                #pragma unroll
                for (int j = 0; j < 8; j++) {
                    const int s = (int)(((j < 4) ? (plo >> (8 * j))
                                                 : (phi >> (8 * (j - 4)))) & 63u);
                    mx = fmaxf(mx, sA[ROT(s, cc)]);
                }
                ps[t] += elu_fast(a2acc[t][r] + mx);
            }
        }
        #pragma unroll
        for (int t = 0; t < 4; t++) {
            ps[t] += __shfl_xor(ps[t], 16, 64);
            ps[t] += __shfl_xor(ps[t], 32, 64);
        }
        if (lane < 16)
            #pragma unroll
            for (int t = 0; t < 4; t++)
                sB[mi * 128 + (nb + t) * 16 + lane] = ps[t];
    }
    __syncthreads();

    // ---- Head
    if (tid < 128) {
        const float p = (sB[tid] + sB[128 + tid] + sB[256 + tid] + sB[384 + tid]) * (1.f / 64.f);
        sB[512 + tid] = p;
    }
    __syncthreads();
    if (tid < 64) {
        float acc = b_o1[tid];
        for (int d = 0; d < 128; d++) acc = fmaf(sB[512 + d], W_o1[d * 64 + tid], acc);
        sB[640 + tid] = elu_fast(acc);
    }
    __syncthreads();
    if (tid < 32) {
        float acc = b_o2[tid];
        for (int d = 0; d < 64; d++) acc = fmaf(sB[640 + d], W_o2[d * 32 + tid], acc);
        sB[704 + tid] = elu_fast(acc);
    }
    __syncthreads();
    if (tid < 4) {
        float acc = b_o3[tid];
        for (int d = 0; d < 32; d++) acc = fmaf(sB[704 + d], W_o3[d * 4 + tid], acc);
        sB[736 + tid] = elu_fast(acc);
    }
    __syncthreads();
    if (tid == 0) {
        float acc = b_o4[0];
        #pragma unroll
        for (int d = 0; d < 4; d++) acc = fmaf(sB[736 + d], W_o4[d], acc);
        out[g] = acc;
        out[G_ + g] = (float)g;
    }
}

// ================= vector fallback (round-4 kernel, inline weight diffs) =================
#define ROTV(r, d)    ((r)*128 + (((d) + 4*(r)) & 127))
#define BS1V(s, c)    (2048 + (s)*128 + (((c) + 4*(s)) & 127))
__global__ __launch_bounds__(TPB, 2)
void fused_vec(const float* __restrict__ x_sv,  const float* __restrict__ x_trk,
               const float* __restrict__ W_sv1, const float* __restrict__ b_sv1,
               const float* __restrict__ W_sv2, const float* __restrict__ b_sv2,
               const float* __restrict__ W_trk1,const float* __restrict__ b_trk1,
               const float* __restrict__ W_trk2,const float* __restrict__ b_trk2,
               const float* __restrict__ W_c1,  const float* __restrict__ b_c1,
               const float* __restrict__ W_c2,  const float* __restrict__ b_c2,
               const float* __restrict__ W_o1,  const float* __restrict__ b_o1,
               const float* __restrict__ W_o2,  const float* __restrict__ b_o2,
               const float* __restrict__ W_o3,  const float* __restrict__ b_o3,
               const float* __restrict__ W_o4,  const float* __restrict__ b_o4,
               float* __restrict__ out)
{
    __shared__ float sA[8192];
    __shared__ float sB[8192];
    __shared__ float sC[4096];
    const int g    = blockIdx.x;
    const int tid  = threadIdx.x;
    const int c128 = tid & 127;
    const int g4   = tid >> 7;
    const int cq   = tid & 31;
    const int c0   = cq * 4;
    const int rg   = tid >> 5;
    const int lane_hi = tid & 32;

    sC[2048 + tid] = x_trk[(size_t)g * 512 + tid];
    if (tid < 32) sC[2560 + tid] = x_sv[(size_t)g * 32 + tid];
    __syncthreads();
    {
        float w[8];
        #pragma unroll
        for (int k = 0; k < 8; k++) w[k] = W_trk1[k * 128 + c128];
        const float b1 = b_trk1[c128];
        #pragma unroll
        for (int i = 0; i < 16; i++) {
            const int r = g4 * 16 + i;
            float acc = b1;
            #pragma unroll
            for (int k = 0; k < 8; k++) acc = fmaf(sC[2048 + r * 8 + k], w[k], acc);
            sB[r * 128 + c128] = elu_ref(acc);
        }
    }
    __syncthreads();
    {
        const int r0 = rg * 4;
        float4 acc[4];
        const float4 bz = *(const float4*)&b_trk2[c0];
        #pragma unroll
        for (int i = 0; i < 4; i++) acc[i] = bz;
        for (int d0 = 0; d0 < 128; d0 += 4) {
            const float4 w0 = *(const float4*)&W_trk2[(d0 + 0) * 128 + c0];
            const float4 w1 = *(const float4*)&W_trk2[(d0 + 1) * 128 + c0];
            const float4 w2 = *(const float4*)&W_trk2[(d0 + 2) * 128 + c0];
            const float4 w3 = *(const float4*)&W_trk2[(d0 + 3) * 128 + c0];
            #pragma unroll
            for (int i = 0; i < 4; i++) {
                const float4 h = *(const float4*)&sB[(r0 + i) * 128 + d0];
                FMA4(acc[i], h.x, w0); FMA4(acc[i], h.y, w1);
                FMA4(acc[i], h.z, w2); FMA4(acc[i], h.w, w3);
            }
        }
        #pragma unroll
        for (int i = 0; i < 4; i++) {
            float4 r;
            r.x = fmaxf(acc[i].x, 0.f); r.y = fmaxf(acc[i].y, 0.f);
            r.z = fmaxf(acc[i].z, 0.f); r.w = fmaxf(acc[i].w, 0.f);
            *(float4*)&sA[ROTV(r0 + i, c0)] = r;
        }
    }
    __syncthreads();
    {
        const float w0 = W_sv1[c128], w1 = W_sv1[128 + c128];
        const float b1 = b_sv1[c128];
        #pragma unroll
        for (int i = 0; i < 4; i++) {
            const int s = g4 * 4 + i;
            sB[s * 128 + c128] =
                elu_ref(fmaf(sC[2560 + s * 2 + 1], w1, fmaf(sC[2560 + s * 2], w0, b1)));
        }
    }
    __syncthreads();
    {
        const int s = rg;
        float4 acc = *(const float4*)&b_sv2[c0];
        for (int d0 = 0; d0 < 128; d0 += 4) {
            const float4 w0 = *(const float4*)&W_sv2[(d0 + 0) * 128 + c0];
            const float4 w1 = *(const float4*)&W_sv2[(d0 + 1) * 128 + c0];
            const float4 w2 = *(const float4*)&W_sv2[(d0 + 2) * 128 + c0];
            const float4 w3 = *(const float4*)&W_sv2[(d0 + 3) * 128 + c0];
            const float4 h = *(const float4*)&sB[s * 128 + d0];
            FMA4(acc, h.x, w0); FMA4(acc, h.y, w1);
            FMA4(acc, h.z, w2); FMA4(acc, h.w, w3);
        }
        float4 r;
        r.x = fmaxf(acc.x, 0.f); r.y = fmaxf(acc.y, 0.f);
        r.z = fmaxf(acc.z, 0.f); r.w = fmaxf(acc.w, 0.f);
        *(float4*)&sC[ROTV(s, c0)] = r;
    }
    __syncthreads();
    unsigned pack1;
    {
        {
            const int s = rg;
            float4 acc = {0.f, 0.f, 0.f, 0.f};
            for (int d0 = 0; d0 < 128; d0 += 4) {
                const float4 e  = *(const float4*)&sC[ROTV(s, d0)];
                const float4 w0 = *(const float4*)&W_c1[(128 + d0 + 0) * 128 + c0];
                const float4 w1 = *(const float4*)&W_c1[(128 + d0 + 1) * 128 + c0];
                const float4 w2 = *(const float4*)&W_c1[(128 + d0 + 2) * 128 + c0];
                const float4 w3 = *(const float4*)&W_c1[(128 + d0 + 3) * 128 + c0];
                FMA4(acc, e.x, w0); FMA4(acc, e.y, w1);
                FMA4(acc, e.z, w2); FMA4(acc, e.w, w3);
            }
            *(float4*)&sC[BS1V(s, c0)] = acc;
        }
        const int q  = tid >> 3;
        const int s0 = tid & 7;
        float d0a = 0.f, d1a = 0.f, n0 = 0.f, n1 = 0.f;
        for (int d0 = 0; d0 < 128; d0 += 4) {
            const float4 t  = *(const float4*)&sA[ROTV(q, d0)];
            const float4 v0 = *(const float4*)&sC[ROTV(s0, d0)];
            const float4 v1 = *(const float4*)&sC[ROTV(s0 + 8, d0)];
            d0a += t.x * v0.x + t.y * v0.y + t.z * v0.z + t.w * v0.w;
            d1a += t.x * v1.x + t.y * v1.y + t.z * v1.z + t.w * v1.w;
            n0  += v0.x * v0.x + v0.y * v0.y + v0.z * v0.z + v0.w * v0.w;
            n1  += v1.x * v1.x + v1.y * v1.y + v1.z * v1.z + v1.w * v1.w;
        }
        float sc0 = fmaf(-2.f, d0a, n0);
        float sc1 = fmaf(-2.f, d1a, n1);
        pack1 = 0u;
        #pragma unroll
        for (int r = 0; r < 8; r++) {
            float bv = sc0; int bs = s0;
            if (sc1 < bv) { bv = sc1; bs = s0 + 8; }
            #pragma unroll
            for (int o = 1; o <= 4; o <<= 1) {
                const float ov = __shfl_xor(bv, o, 8);
                const int   os = __shfl_xor(bs, o, 8);
                if (ov < bv || (ov == bv && os < bs)) { bv = ov; bs = os; }
            }
            pack1 |= (unsigned)bs << (4 * r);
            if (bs == s0)     sc0 = INF_F;
            if (bs == s0 + 8) sc1 = INF_F;
        }
    }
    __syncthreads();
    float4 a2v[4];
    {
        const int q0 = rg * 4;
        float4 a1[4];
        const float4 bc1 = *(const float4*)&b_c1[c0];
        const float4 bc2 = *(const float4*)&b_c2[c0];
        #pragma unroll
        for (int i = 0; i < 4; i++) { a1[i] = bc1; a2v[i] = bc2; }
        for (int d0 = 0; d0 < 128; d0 += 4) {
            float4 t[4];
            #pragma unroll
            for (int i = 0; i < 4; i++) t[i] = *(const float4*)&sA[ROTV(q0 + i, d0)];
            #pragma unroll
            for (int dj = 0; dj < 4; dj++) {
                float4 wv;
                const float4 wa = *(const float4*)&W_c1[(d0 + dj) * 128 + c0];
                const float4 wb = *(const float4*)&W_c1[(128 + d0 + dj) * 128 + c0];
                wv.x = wa.x - wb.x; wv.y = wa.y - wb.y;
                wv.z = wa.z - wb.z; wv.w = wa.w - wb.w;
                FMA4(a1[0], ((const float*)&t[0])[dj], wv);
                FMA4(a1[1], ((const float*)&t[1])[dj], wv);
                FMA4(a1[2], ((const float*)&t[2])[dj], wv);
                FMA4(a1[3], ((const float*)&t[3])[dj], wv);
            }
            #pragma unroll
            for (int dj = 0; dj < 4; dj++) {
                float4 wv;
                const float4 wa = *(const float4*)&W_c2[(d0 + dj) * 128 + c0];
                const float4 wb = *(const float4*)&W_c2[(128 + d0 + dj) * 128 + c0];
                wv.x = wa.x - wb.x; wv.y = wa.y - wb.y;
                wv.z = wa.z - wb.z; wv.w = wa.w - wb.w;
                FMA4(a2v[0], ((const float*)&t[0])[dj], wv);
                FMA4(a2v[1], ((const float*)&t[1])[dj], wv);
                FMA4(a2v[2], ((const float*)&t[2])[dj], wv);
                FMA4(a2v[3], ((const float*)&t[3])[dj], wv);
            }
        }
        #pragma unroll
        for (int i = 0; i < 4; i++) {
            const int q = q0 + i;
            const unsigned pk = __shfl(pack1, 8 * i + lane_hi);
            float4 m = {-INF_F, -INF_F, -INF_F, -INF_F};
            #pragma unroll
            for (int j = 0; j < 8; j++) {
                const int s = (int)((pk >> (4 * j)) & 15u);
                const float4 b = *(const float4*)&sC[BS1V(s, c0)];
                MAX4(m, b);
            }
            float4 f;
            f.x = elu_ref(a1[i].x + m.x); f.y = elu_ref(a1[i].y + m.y);
            f.z = elu_ref(a1[i].z + m.z); f.w = elu_ref(a1[i].w + m.w);
            *(float4*)&sB[ROTV(q, c0)] = f;
        }
    }
    __syncthreads();
    {
        const int s  = tid & 63;
        const int q0 = (tid >> 6) * 8;
        float acc[8];
        #pragma unroll
        for (int i = 0; i < 8; i++) acc[i] = 0.f;
        float nrm = 0.f;
        for (int d0 = 0; d0 < 128; d0 += 4) {
            const float4 f = *(const float4*)&sB[ROTV(s, d0)];
            nrm = fmaf(f.x, f.x, nrm); nrm = fmaf(f.y, f.y, nrm);
            nrm = fmaf(f.z, f.z, nrm); nrm = fmaf(f.w, f.w, nrm);
            #pragma unroll
            for (int i = 0; i < 8; i++) {
                const float4 t = *(const float4*)&sA[ROTV(q0 + i, d0)];
                acc[i] = fmaf(t.x, f.x, acc[i]); acc[i] = fmaf(t.y, f.y, acc[i]);
                acc[i] = fmaf(t.z, f.z, acc[i]); acc[i] = fmaf(t.w, f.w, acc[i]);
            }
        }
        #pragma unroll
        for (int i = 0; i < 8; i++)
            sC[(q0 + i) * 64 + s] = fmaf(-2.f, acc[i], nrm);
    }
    __syncthreads();
    unsigned lo2, hi2;
    {
        const int q = tid >> 3;
        const int j = tid & 7;
        float v[8];
        *(float4*)&v[0] = *(const float4*)&sC[q * 64 + 8 * j];
        *(float4*)&v[4] = *(const float4*)&sC[q * 64 + 8 * j + 4];
        lo2 = 0u; hi2 = 0u;
        #pragma unroll
        for (int r = 0; r < 8; r++) {
            float bv = v[0]; int bs = 8 * j;
            #pragma unroll
            for (int t = 1; t < 8; t++)
                if (v[t] < bv) { bv = v[t]; bs = 8 * j + t; }
            #pragma unroll
            for (int o = 1; o <= 4; o <<= 1) {
                const float ov = __shfl_xor(bv, o, 8);
                const int   os = __shfl_xor(bs, o, 8);
                if (ov < bv || (ov == bv && os < bs)) { bv = ov; bs = os; }
            }
            if (r < 4) lo2 |= (unsigned)bs << (8 * r);
            else       hi2 |= (unsigned)bs << (8 * (r - 4));
            #pragma unroll
            for (int t = 0; t < 8; t++)
                if (bs == 8 * j + t) v[t] = INF_F;
        }
        const int r0 = rg * 4;
        float4 acc[4];
        #pragma unroll
        for (int i = 0; i < 4; i++) acc[i] = make_float4(0.f, 0.f, 0.f, 0.f);
        for (int d0 = 0; d0 < 128; d0 += 4) {
            const float4 w0 = *(const float4*)&W_c2[(128 + d0 + 0) * 128 + c0];
            const float4 w1 = *(const float4*)&W_c2[(128 + d0 + 1) * 128 + c0];
            const float4 w2 = *(const float4*)&W_c2[(128 + d0 + 2) * 128 + c0];
            const float4 w3 = *(const float4*)&W_c2[(128 + d0 + 3) * 128 + c0];
            #pragma unroll
            for (int i = 0; i < 4; i++) {
                const float4 f = *(const float4*)&sB[ROTV(r0 + i, d0)];
                FMA4(acc[i], f.x, w0); FMA4(acc[i], f.y, w1);
                FMA4(acc[i], f.z, w2); FMA4(acc[i], f.w, w3);
            }
        }
        #pragma unroll
        for (int i = 0; i < 4; i++)
            *(float4*)&sA[ROTV(r0 + i, c0)] = acc[i];
    }
    __syncthreads();
    {
        const int q0 = rg * 4;
        float4 ps = {0.f, 0.f, 0.f, 0.f};
        #pragma unroll
        for (int i = 0; i < 4; i++) {
            const unsigned plo = __shfl(lo2, 8 * i + lane_hi);
            const unsigned phi = __shfl(hi2, 8 * i + lane_hi);
            float4 m = {-INF_F, -INF_F, -INF_F, -INF_F};
            #pragma unroll
            for (int j = 0; j < 8; j++) {
                const int s = (int)(((j < 4) ? (plo >> (8 * j)) : (phi >> (8 * (j - 4)))) & 63u);
                const float4 b = *(const float4*)&sA[ROTV(s, c0)];
                MAX4(m, b);
            }
            ps.x += elu_ref(a2v[i].x + m.x); ps.y += elu_ref(a2v[i].y + m.y);
            ps.z += elu_ref(a2v[i].z + m.z); ps.w += elu_ref(a2v[i].w + m.w);
        }
        *(float4*)&sB[rg * 128 + c0] = ps;
    }
    __syncthreads();
    if (tid < 128) {
        float p = 0.f;
        #pragma unroll
        for (int t = 0; t < 16; t++) p += sB[t * 128 + tid];
        sB[2048 + tid] = p * (1.f / 64.f);
    }
    __syncthreads();
    if (tid < 64) {
        float acc = b_o1[tid];
        for (int d = 0; d < 128; d++) acc = fmaf(sB[2048 + d], W_o1[d * 64 + tid], acc);
        sB[2176 + tid] = elu_ref(acc);
    }
    __syncthreads();
    if (tid < 32) {
        float acc = b_o2[tid];
        for (int d = 0; d < 64; d++) acc = fmaf(sB[2176 + d], W_o2[d * 32 + tid], acc);
        sB[2240 + tid] = elu_ref(acc);
    }
    __syncthreads();
    if (tid < 4) {
        float acc = b_o3[tid];
        for (int d = 0; d < 32; d++) acc = fmaf(sB[2240 + d], W_o3[d * 4 + tid], acc);
        sB[2272 + tid] = elu_ref(acc);
    }
    __syncthreads();
    if (tid == 0) {
        float acc = b_o4[0];
        #pragma unroll
        for (int d = 0; d < 4; d++) acc = fmaf(sB[2272 + d], W_o4[d], acc);
        out[g] = acc;
        out[G_ + g] = (float)g;
    }
}

extern "C" void kernel_launch(void* const* d_in, const int* in_sizes, int n_in,
                              void* d_out, int out_size, void* d_ws, size_t ws_size,
                              hipStream_t stream) {
    const float* x_sv   = (const float*)d_in[0];
    const float* x_trk  = (const float*)d_in[1];
    const float* W_sv1  = (const float*)d_in[2];
    const float* b_sv1  = (const float*)d_in[3];
    const float* W_sv2  = (const float*)d_in[4];
    const float* b_sv2  = (const float*)d_in[5];
    const float* W_trk1 = (const float*)d_in[6];
    const float* b_trk1 = (const float*)d_in[7];
    const float* W_trk2 = (const float*)d_in[8];
    const float* b_trk2 = (const float*)d_in[9];
    const float* W_c1   = (const float*)d_in[10];
    const float* b_c1   = (const float*)d_in[11];
    const float* W_c2   = (const float*)d_in[12];
    const float* b_c2   = (const float*)d_in[13];
    const float* W_o1   = (const float*)d_in[14];
    const float* b_o1   = (const float*)d_in[15];
    const float* W_o2   = (const float*)d_in[16];
    const float* b_o2   = (const float*)d_in[17];
    const float* W_o3   = (const float*)d_in[18];
    const float* b_o3   = (const float*)d_in[19];
    const float* W_o4   = (const float*)d_in[20];
    const float* b_o4   = (const float*)d_in[21];
    float* out = (float*)d_out;

    const size_t WS_NEED = (size_t)6 * 16384 * sizeof(unsigned short); // 192 KB
    if (ws_size >= WS_NEED && d_ws != nullptr) {
        unsigned short* wsu = (unsigned short*)d_ws;
        prep_pack<<<384, 256, 0, stream>>>(W_trk2, W_sv2, W_c1, W_c2, wsu);
        fused_mfma<<<G_, TPB, 0, stream>>>(x_sv, x_trk, W_sv1, b_sv1, b_sv2,
                                           W_trk1, b_trk1, b_trk2, b_c1, b_c2,
                                           W_o1, b_o1, W_o2, b_o2, W_o3, b_o3,
                                           W_o4, b_o4, wsu, out);
    } else {
        fused_vec<<<G_, TPB, 0, stream>>>(x_sv, x_trk, W_sv1, b_sv1, W_sv2, b_sv2,
                                          W_trk1, b_trk1, W_trk2, b_trk2,
                                          W_c1, b_c1, W_c2, b_c2,
                                          W_o1, b_o1, W_o2, b_o2, W_o3, b_o3,
                                          W_o4, b_o4, out);
    }
}

// Round 15
// 189.499 us; speedup vs baseline: 1.1551x; 1.1551x over previous
//
#include <hip/hip_runtime.h>

#define G_    1024
#define TPB   512
#define INF_F 3.4e38f

typedef __attribute__((ext_vector_type(8))) short short8;
typedef __attribute__((ext_vector_type(4))) float f32x4;

__device__ __forceinline__ float elu_fast(float x) { return x > 0.f ? x : __expf(x) - 1.f; }
__device__ __forceinline__ float elu_ref(float x)  { return x > 0.f ? x : expm1f(x); }

// Rotated row layouts (rotation multiple of 4 -> float4 stays aligned, 2-way banks)
#define ROT(r, d)    ((r)*128 + (((d) + 4*(r)) & 127))
#define BS1(s, c)    (2048 + (s)*128 + (((c) + 4*(s)) & 127))

#define FMA4(acc_, sc_, wv_) do { (acc_).x = fmaf((sc_),(wv_).x,(acc_).x); \
                                  (acc_).y = fmaf((sc_),(wv_).y,(acc_).y); \
                                  (acc_).z = fmaf((sc_),(wv_).z,(acc_).z); \
                                  (acc_).w = fmaf((sc_),(wv_).w,(acc_).w); } while(0)
#define MAX4(mm_, bb_)       do { (mm_).x = fmaxf((mm_).x,(bb_).x); \
                                  (mm_).y = fmaxf((mm_).y,(bb_).y); \
                                  (mm_).z = fmaxf((mm_).z,(bb_).z); \
                                  (mm_).w = fmaxf((mm_).w,(bb_).w); } while(0)

#define MFMA1(acc_, A_, B_) \
    acc_ = __builtin_amdgcn_mfma_f32_16x16x32_bf16((A_), (B_), (acc_), 0, 0, 0)

union U8 { unsigned d[4]; short8 v; };

// RNE-pack 8 contiguous fp32 (two float4s) into one bf16 fragment (4 VGPRs).
// Single-plane: measured absmax 6e-6 end-to-end (R13) — no kNN flips.
__device__ __forceinline__ short8 pack_frag(const float* p0, const float* p1) {
    float xs[8];
    *(float4*)&xs[0] = *(const float4*)p0;
    *(float4*)&xs[4] = *(const float4*)p1;
    U8 uo;
    #pragma unroll
    for (int k = 0; k < 4; k++) {
        unsigned u0 = __float_as_uint(xs[2 * k]);
        unsigned u1 = __float_as_uint(xs[2 * k + 1]);
        u0 = u0 + 0x7FFFu + ((u0 >> 16) & 1u);   // round-to-nearest-even
        u1 = u1 + 0x7FFFu + ((u1 >> 16) & 1u);
        uo.d[k] = (u0 >> 16) | (u1 & 0xFFFF0000u);
    }
    return uo.v;
}

__device__ __forceinline__ unsigned short bf16_of(float v) {
    unsigned u = __float_as_uint(v);
    u = u + 0x7FFFu + ((u >> 16) & 1u);
    return (unsigned short)(u >> 16);
}
__device__ __forceinline__ float f32_of(unsigned short h) {
    return __uint_as_float((unsigned)h << 16);
}

// prep: RNE bf16 single plane of 6 matrices, packed in B-fragment order.
// matrices: 0=W_trk2 1=W_sv2 2=Wc1_bot 3=Wd1 4=Wd2 5=Wc2_bot
__global__ void prep_pack(const float* __restrict__ Wtrk2, const float* __restrict__ Wsv2,
                          const float* __restrict__ Wc1,   const float* __restrict__ Wc2,
                          unsigned short* __restrict__ wsu) {
    const int o = blockIdx.x * 256 + threadIdx.x;
    if (o >= 6 * 16384) return;
    const int m = o >> 14, pos = o & 16383;
    const int j = pos & 7, lane = (pos >> 3) & 63, tile = pos >> 9;
    const int ks = tile >> 3, ni = tile & 7;
    const int d = ks * 32 + (lane >> 4) * 8 + j;
    const int c = ni * 16 + (lane & 15);
    const int e = d * 128 + c;
    float v;
    switch (m) {
        case 0: v = Wtrk2[e]; break;
        case 1: v = Wsv2[e]; break;
        case 2: v = Wc1[16384 + e]; break;
        case 3: v = Wc1[e] - Wc1[16384 + e]; break;
        case 4: v = Wc2[e] - Wc2[16384 + e]; break;
        default: v = Wc2[16384 + e]; break;
    }
    wsu[m * 16384 + pos] = bf16_of(v);
}

#define LOADB1(B_, m_, pos_) B_ = *(const short8*)(wsu + (m_) * 16384 + (pos_))

__global__ __launch_bounds__(TPB, 4)
void fused_mfma(const float* __restrict__ x_sv,  const float* __restrict__ x_trk,
                const float* __restrict__ W_sv1, const float* __restrict__ b_sv1,
                const float* __restrict__ b_sv2,
                const float* __restrict__ W_trk1,const float* __restrict__ b_trk1,
                const float* __restrict__ b_trk2,
                const float* __restrict__ b_c1,  const float* __restrict__ b_c2,
                const float* __restrict__ W_o1,  const float* __restrict__ b_o1,
                const float* __restrict__ W_o2,  const float* __restrict__ b_o2,
                const float* __restrict__ W_o3,  const float* __restrict__ b_o3,
                const float* __restrict__ W_o4,  const float* __restrict__ b_o4,
                const unsigned short* __restrict__ wsu,
                float* __restrict__ out)
{
    __shared__ float sA[8192];   // 32 KB : T (rot) -> bsrc2 (rot)
    __shared__ float sB[8192];   // 32 KB : h_trk/h_sv (rot) + svnorm -> scores1+packs -> f1 (rot) -> idx2+pool+head
    __shared__ float sC[4096];   // 16 KB : x stage + sv_emb (rot) + bsrc1 -> f1norm+scores2 -> a2 (bf16)
    unsigned* sBu = (unsigned*)sB;
    unsigned short* sCs = (unsigned short*)sC;

    const int g    = blockIdx.x;
    const int tid  = threadIdx.x;
    const int c128 = tid & 127;
    const int g4   = tid >> 7;
    const int wv   = tid >> 6;          // wave 0..7
    const int lane = tid & 63;
    const int quad = lane >> 4;
    const int ln   = lane & 15;

    // ---- P0: stage inputs
    sC[2048 + tid] = x_trk[(size_t)g * 512 + tid];
    if (tid < 32) sC[2560 + tid] = x_sv[(size_t)g * 32 + tid];
    __syncthreads();

    // ---- P1: trk MLP layer 1 -> h in sB (rot)
    {
        float w[8];
        #pragma unroll
        for (int k = 0; k < 8; k++) w[k] = W_trk1[k * 128 + c128];
        const float b1 = b_trk1[c128];
        #pragma unroll
        for (int i = 0; i < 16; i++) {
            const int r = g4 * 16 + i;
            float xr[8];
            *(float4*)&xr[0] = *(const float4*)&sC[2048 + r * 8];
            *(float4*)&xr[4] = *(const float4*)&sC[2048 + r * 8 + 4];
            float acc = b1;
            #pragma unroll
            for (int k = 0; k < 8; k++) acc = fmaf(xr[k], w[k], acc);
            sB[ROT(r, c128)] = elu_fast(acc);
        }
    }
    __syncthreads();

    // ---- P2 (MFMA): T = relu(h @ W_trk2 + b) -> sA (rot)
    {
        const int mi = wv >> 1, nb = (wv & 1) * 4;
        const int row = mi * 16 + ln;
        f32x4 acc[4];
        #pragma unroll
        for (int t = 0; t < 4; t++) {
            const float bz = b_trk2[(nb + t) * 16 + ln];
            acc[t] = (f32x4){bz, bz, bz, bz};
        }
        #pragma unroll 1
        for (int ks = 0; ks < 4; ks++) {
            const int k0 = ks * 32 + quad * 8;
            const short8 A = pack_frag(&sB[ROT(row, k0)], &sB[ROT(row, k0 + 4)]);
            #pragma unroll
            for (int t = 0; t < 4; t++) {
                const int pos = ((ks * 8 + (nb + t)) * 64 + lane) * 8;
                short8 B;
                LOADB1(B, 0, pos);
                MFMA1(acc[t], A, B);
            }
        }
        #pragma unroll
        for (int t = 0; t < 4; t++)
            #pragma unroll
            for (int r = 0; r < 4; r++)
                sA[ROT(mi * 16 + quad * 4 + r, (nb + t) * 16 + ln)] = fmaxf(acc[t][r], 0.f);
    }
    __syncthreads();

    // ---- P3: sv MLP layer 1 -> h_sv rows 0..15 in sB (rot)
    {
        const float w0 = W_sv1[c128], w1 = W_sv1[128 + c128];
        const float b1 = b_sv1[c128];
        #pragma unroll
        for (int i = 0; i < 4; i++) {
            const int s = g4 * 4 + i;
            sB[ROT(s, c128)] =
                elu_fast(fmaf(sC[2560 + s * 2 + 1], w1, fmaf(sC[2560 + s * 2], w0, b1)));
        }
    }
    __syncthreads();

    // ---- P3b (MFMA): sv_emb -> sC rows 0..15 (rot); per-wave col-partial norms -> sB[2048+]
    {
        const int ni = wv;
        const float bz = b_sv2[ni * 16 + ln];
        f32x4 acc = (f32x4){bz, bz, bz, bz};
        #pragma unroll 1
        for (int ks = 0; ks < 4; ks++) {
            const int k0 = ks * 32 + quad * 8;
            const short8 A = pack_frag(&sB[ROT(ln, k0)], &sB[ROT(ln, k0 + 4)]);
            const int pos = ((ks * 8 + ni) * 64 + lane) * 8;
            short8 B;
            LOADB1(B, 1, pos);
            MFMA1(acc, A, B);
        }
        #pragma unroll
        for (int r = 0; r < 4; r++) {
            const float v = fmaxf(acc[r], 0.f);
            sC[ROT(quad * 4 + r, ni * 16 + ln)] = v;
            float p = v * v;
            #pragma unroll
            for (int o = 1; o <= 8; o <<= 1) p += __shfl_xor(p, o, 16);
            if (ln == 0) sB[2048 + ni * 16 + quad * 4 + r] = p;
        }
    }
    __syncthreads();

    // ---- B1 (MFMA): bsrc1 = sv @ Wc1_bot -> sC[2048..]; P4 (waves 0..3): scores1 -> sB
    {
        const int ni = wv;
        const bool doP4 = (wv < 4);
        f32x4 accB = (f32x4){0.f, 0.f, 0.f, 0.f};
        f32x4 accS = (f32x4){0.f, 0.f, 0.f, 0.f};
        #pragma unroll 1
        for (int ks = 0; ks < 4; ks++) {
            const int k0 = ks * 32 + quad * 8;
            const short8 S = pack_frag(&sC[ROT(ln, k0)], &sC[ROT(ln, k0 + 4)]);
            const int pos = ((ks * 8 + ni) * 64 + lane) * 8;
            short8 B;
            LOADB1(B, 2, pos);
            MFMA1(accB, S, B);
            if (doP4) {
                const int row = wv * 16 + ln;   // T row (mi = wv)
                const short8 T = pack_frag(&sA[ROT(row, k0)], &sA[ROT(row, k0 + 4)]);
                MFMA1(accS, T, S);
            }
        }
        #pragma unroll
        for (int r = 0; r < 4; r++)
            sC[BS1(quad * 4 + r, ni * 16 + ln)] = accB[r];
        if (doP4) {
            float nsv = 0.f;
            #pragma unroll
            for (int p = 0; p < 8; p++) nsv += sB[2048 + p * 16 + ln];
            #pragma unroll
            for (int r = 0; r < 4; r++)
                sB[(wv * 16 + quad * 4 + r) * 17 + ln] = fmaf(-2.f, accS[r], nsv);
        }
    }
    __syncthreads();

    // ---- topk1: top-8 of 16 (shfl) -> packs sBu[1088+q]
    {
        const int q  = tid >> 3;
        const int s0 = tid & 7;
        float sc0 = sB[q * 17 + s0];
        float sc1 = sB[q * 17 + s0 + 8];
        unsigned pack1 = 0u;
        #pragma unroll
        for (int r = 0; r < 8; r++) {
            float bv = sc0; int bs = s0;
            if (sc1 < bv) { bv = sc1; bs = s0 + 8; }
            #pragma unroll
            for (int o = 1; o <= 4; o <<= 1) {
                const float ov = __shfl_xor(bv, o, 8);
                const int   os = __shfl_xor(bs, o, 8);
                if (ov < bv || (ov == bv && os < bs)) { bv = ov; bs = os; }
            }
            pack1 |= (unsigned)bs << (4 * r);
            if (bs == s0)     sc0 = INF_F;
            if (bs == s0 + 8) sc1 = INF_F;
        }
        if (s0 == 0) sBu[1088 + q] = pack1;
    }
    __syncthreads();

    // ---- Phase6 (MFMA, a1 ONLY): a1 = T @ Wd1 + b1 ; f1 = elu(a1 + max bsrc1[idx]) -> sB ;
    //      f1-norms -> sC[0..127]
    {
        const int mi = wv >> 1, nb = (wv & 1) * 4;
        const int row = mi * 16 + ln;
        f32x4 a1acc[4];
        #pragma unroll
        for (int t = 0; t < 4; t++) {
            const float bz1 = b_c1[(nb + t) * 16 + ln];
            a1acc[t] = (f32x4){bz1, bz1, bz1, bz1};
        }
        #pragma unroll 1
        for (int ks = 0; ks < 4; ks++) {
            const int k0 = ks * 32 + quad * 8;
            const short8 A = pack_frag(&sA[ROT(row, k0)], &sA[ROT(row, k0 + 4)]);
            #pragma unroll
            for (int t = 0; t < 4; t++) {
                const int pos = ((ks * 8 + (nb + t)) * 64 + lane) * 8;
                short8 B;
                LOADB1(B, 3, pos);
                MFMA1(a1acc[t], A, B);
            }
        }
        // read packs into regs BEFORE barrier (f1 writes overwrite sB row 8 = sBu[1088..])
        unsigned pk[4];
        #pragma unroll
        for (int r = 0; r < 4; r++) pk[r] = sBu[1088 + mi * 16 + quad * 4 + r];
        __syncthreads();
        float np[4] = {0.f, 0.f, 0.f, 0.f};
        #pragma unroll
        for (int t = 0; t < 4; t++) {
            const int cc = (nb + t) * 16 + ln;
            #pragma unroll
            for (int r = 0; r < 4; r++) {
                float mx = -INF_F;
                #pragma unroll
                for (int j = 0; j < 8; j++) {
                    const int s = (int)((pk[r] >> (4 * j)) & 15u);
                    mx = fmaxf(mx, sC[BS1(s, cc)]);
                }
                const float f = elu_fast(a1acc[t][r] + mx);
                sB[ROT(mi * 16 + quad * 4 + r, cc)] = f;
                np[r] = fmaf(f, f, np[r]);
            }
        }
        #pragma unroll
        for (int r = 0; r < 4; r++) {
            #pragma unroll
            for (int o = 1; o <= 8; o <<= 1) np[r] += __shfl_xor(np[r], o, 16);
            if (ln == 0) sC[(wv & 1) * 64 + mi * 16 + quad * 4 + r] = np[r];
        }
    }
    __syncthreads();

    // ---- Phase7 (MFMA): scores2[q][s] = n_s - 2 T_q . f1_s -> sC[q*64+s]
    {
        const int mi = wv >> 1, nia = (wv & 1) * 2;
        const int row = mi * 16 + ln;
        float ns[2];
        #pragma unroll
        for (int u = 0; u < 2; u++) {
            const int s = (nia + u) * 16 + ln;
            ns[u] = sC[s] + sC[64 + s];
        }
        __syncthreads();   // norms read before scores overwrite sC
        f32x4 acc[2];
        acc[0] = (f32x4){0.f, 0.f, 0.f, 0.f};
        acc[1] = (f32x4){0.f, 0.f, 0.f, 0.f};
        #pragma unroll 1
        for (int ks = 0; ks < 4; ks++) {
            const int k0 = ks * 32 + quad * 8;
            const short8 A = pack_frag(&sA[ROT(row, k0)], &sA[ROT(row, k0 + 4)]);
            #pragma unroll
            for (int u = 0; u < 2; u++) {
                const int srow = (nia + u) * 16 + ln;
                const short8 B = pack_frag(&sB[ROT(srow, k0)], &sB[ROT(srow, k0 + 4)]);
                MFMA1(acc[u], A, B);
            }
        }
        #pragma unroll
        for (int u = 0; u < 2; u++) {
            const int s = (nia + u) * 16 + ln;
            #pragma unroll
            for (int r = 0; r < 4; r++)
                sC[(mi * 16 + quad * 4 + r) * 64 + s] = fmaf(-2.f, acc[u][r], ns[u]);
        }
    }
    __syncthreads();

    // ---- topk2: top-8 of 64 (shfl) ; lo2/hi2 kept in regs until post-P8d handoff
    unsigned lo2, hi2;
    {
        const int q = tid >> 3;
        const int j = tid & 7;
        float v[8];
        *(float4*)&v[0] = *(const float4*)&sC[q * 64 + 8 * j];
        *(float4*)&v[4] = *(const float4*)&sC[q * 64 + 8 * j + 4];
        lo2 = 0u; hi2 = 0u;
        #pragma unroll
        for (int r = 0; r < 8; r++) {
            float bv = v[0]; int bs = 8 * j;
            #pragma unroll
            for (int t = 1; t < 8; t++)
                if (v[t] < bv) { bv = v[t]; bs = 8 * j + t; }
            #pragma unroll
            for (int o = 1; o <= 4; o <<= 1) {
                const float ov = __shfl_xor(bv, o, 8);
                const int   os = __shfl_xor(bs, o, 8);
                if (ov < bv || (ov == bv && os < bs)) { bv = ov; bs = os; }
            }
            if (r < 4) lo2 |= (unsigned)bs << (8 * r);
            else       hi2 |= (unsigned)bs << (8 * (r - 4));
            #pragma unroll
            for (int t = 0; t < 8; t++)
                if (bs == 8 * j + t) v[t] = INF_F;
        }
    }
    __syncthreads();   // all score reads done; sC is now fully dead

    // ---- Phase8a (MFMA): a2 = T @ Wd2 + b2 (sA still holds T); park as bf16 in sC
    //      at per-thread-linear slots (same thread stores & reloads its own 16 values)
    {
        const int mi = wv >> 1, nb = (wv & 1) * 4;
        const int row = mi * 16 + ln;
        f32x4 a2acc[4];
        #pragma unroll
        for (int t = 0; t < 4; t++) {
            const float bz2 = b_c2[(nb + t) * 16 + ln];
            a2acc[t] = (f32x4){bz2, bz2, bz2, bz2};
        }
        #pragma unroll 1
        for (int ks = 0; ks < 4; ks++) {
            const int k0 = ks * 32 + quad * 8;
            const short8 A = pack_frag(&sA[ROT(row, k0)], &sA[ROT(row, k0 + 4)]);
            #pragma unroll
            for (int t = 0; t < 4; t++) {
                const int pos = ((ks * 8 + (nb + t)) * 64 + lane) * 8;
                short8 B;
                LOADB1(B, 4, pos);
                MFMA1(a2acc[t], A, B);
            }
        }
        #pragma unroll
        for (int t = 0; t < 4; t++)
            #pragma unroll
            for (int r = 0; r < 4; r++)
                sCs[tid * 16 + t * 4 + r] = bf16_of(a2acc[t][r]);
    }
    __syncthreads();   // a2 done reading T before P8d overwrites sA

    // ---- P8d (MFMA): bsrc2 = f1 @ Wc2_bot -> sA
    {
        const int mi = wv >> 1, nb = (wv & 1) * 4;
        const int row = mi * 16 + ln;
        f32x4 acc[4];
        #pragma unroll
        for (int t = 0; t < 4; t++) acc[t] = (f32x4){0.f, 0.f, 0.f, 0.f};
        #pragma unroll 1
        for (int ks = 0; ks < 4; ks++) {
            const int k0 = ks * 32 + quad * 8;
            const short8 A = pack_frag(&sB[ROT(row, k0)], &sB[ROT(row, k0 + 4)]);
            #pragma unroll
            for (int t = 0; t < 4; t++) {
                const int pos = ((ks * 8 + (nb + t)) * 64 + lane) * 8;
                short8 B;
                LOADB1(B, 5, pos);
                MFMA1(acc[t], A, B);
            }
        }
        #pragma unroll
        for (int t = 0; t < 4; t++)
            #pragma unroll
            for (int r = 0; r < 4; r++)
                sA[ROT(mi * 16 + quad * 4 + r, (nb + t) * 16 + ln)] = acc[t][r];
    }
    __syncthreads();   // f1 now dead -> sB free for idx2 handoff

    // ---- idx2 handoff -> sBu[1024 + 2q] (dead f1 space)
    if ((tid & 7) == 0) {
        const int q = tid >> 3;
        sBu[1024 + 2 * q]     = lo2;
        sBu[1024 + 2 * q + 1] = hi2;
    }
    __syncthreads();

    // ---- Phase9: f2 = elu(a2 + max bsrc2[idx]) ; pool -> sB[0..511]
    {
        const int mi = wv >> 1, nb = (wv & 1) * 4;
        float ps[4] = {0.f, 0.f, 0.f, 0.f};
        #pragma unroll
        for (int t = 0; t < 4; t++) {
            const int cc = (nb + t) * 16 + ln;
            #pragma unroll
            for (int r = 0; r < 4; r++) {
                const int rr = mi * 16 + quad * 4 + r;
                const unsigned plo = sBu[1024 + 2 * rr];
                const unsigned phi = sBu[1024 + 2 * rr + 1];
                float mx = -INF_F;
                #pragma unroll
                for (int j = 0; j < 8; j++) {
                    const int s = (int)(((j < 4) ? (plo >> (8 * j))
                                                 : (phi >> (8 * (j - 4)))) & 63u);
                    mx = fmaxf(mx, sA[ROT(s, cc)]);
                }
                const float a2v = f32_of(sCs[tid * 16 + t * 4 + r]);
                ps[t] += elu_fast(a2v + mx);
            }
        }
        #pragma unroll
        for (int t = 0; t < 4; t++) {
            ps[t] += __shfl_xor(ps[t], 16, 64);
            ps[t] += __shfl_xor(ps[t], 32, 64);
        }
        if (lane < 16)
            #pragma unroll
            for (int t = 0; t < 4; t++)
                sB[mi * 128 + (nb + t) * 16 + lane] = ps[t];
    }
    __syncthreads();

    // ---- Head
    if (tid < 128) {
        const float p = (sB[tid] + sB[128 + tid] + sB[256 + tid] + sB[384 + tid]) * (1.f / 64.f);
        sB[512 + tid] = p;
    }
    __syncthreads();
    if (tid < 64) {
        float acc = b_o1[tid];
        for (int d = 0; d < 128; d++) acc = fmaf(sB[512 + d], W_o1[d * 64 + tid], acc);
        sB[640 + tid] = elu_fast(acc);
    }
    __syncthreads();
    if (tid < 32) {
        float acc = b_o2[tid];
        for (int d = 0; d < 64; d++) acc = fmaf(sB[640 + d], W_o2[d * 32 + tid], acc);
        sB[704 + tid] = elu_fast(acc);
    }
    __syncthreads();
    if (tid < 4) {
        float acc = b_o3[tid];
        for (int d = 0; d < 32; d++) acc = fmaf(sB[704 + d], W_o3[d * 4 + tid], acc);
        sB[736 + tid] = elu_fast(acc);
    }
    __syncthreads();
    if (tid == 0) {
        float acc = b_o4[0];
        #pragma unroll
        for (int d = 0; d < 4; d++) acc = fmaf(sB[736 + d], W_o4[d], acc);
        out[g] = acc;
        out[G_ + g] = (float)g;
    }
}

// ================= vector fallback (round-4 kernel, inline weight diffs) =================
#define ROTV(r, d)    ((r)*128 + (((d) + 4*(r)) & 127))
#define BS1V(s, c)    (2048 + (s)*128 + (((c) + 4*(s)) & 127))
__global__ __launch_bounds__(TPB, 2)
void fused_vec(const float* __restrict__ x_sv,  const float* __restrict__ x_trk,
               const float* __restrict__ W_sv1, const float* __restrict__ b_sv1,
               const float* __restrict__ W_sv2, const float* __restrict__ b_sv2,
               const float* __restrict__ W_trk1,const float* __restrict__ b_trk1,
               const float* __restrict__ W_trk2,const float* __restrict__ b_trk2,
               const float* __restrict__ W_c1,  const float* __restrict__ b_c1,
               const float* __restrict__ W_c2,  const float* __restrict__ b_c2,
               const float* __restrict__ W_o1,  const float* __restrict__ b_o1,
               const float* __restrict__ W_o2,  const float* __restrict__ b_o2,
               const float* __restrict__ W_o3,  const float* __restrict__ b_o3,
               const float* __restrict__ W_o4,  const float* __restrict__ b_o4,
               float* __restrict__ out)
{
    __shared__ float sA[8192];
    __shared__ float sB[8192];
    __shared__ float sC[4096];
    const int g    = blockIdx.x;
    const int tid  = threadIdx.x;
    const int c128 = tid & 127;
    const int g4   = tid >> 7;
    const int cq   = tid & 31;
    const int c0   = cq * 4;
    const int rg   = tid >> 5;
    const int lane_hi = tid & 32;

    sC[2048 + tid] = x_trk[(size_t)g * 512 + tid];
    if (tid < 32) sC[2560 + tid] = x_sv[(size_t)g * 32 + tid];
    __syncthreads();
    {
        float w[8];
        #pragma unroll
        for (int k = 0; k < 8; k++) w[k] = W_trk1[k * 128 + c128];
        const float b1 = b_trk1[c128];
        #pragma unroll
        for (int i = 0; i < 16; i++) {
            const int r = g4 * 16 + i;
            float acc = b1;
            #pragma unroll
            for (int k = 0; k < 8; k++) acc = fmaf(sC[2048 + r * 8 + k], w[k], acc);
            sB[r * 128 + c128] = elu_ref(acc);
        }
    }
    __syncthreads();
    {
        const int r0 = rg * 4;
        float4 acc[4];
        const float4 bz = *(const float4*)&b_trk2[c0];
        #pragma unroll
        for (int i = 0; i < 4; i++) acc[i] = bz;
        for (int d0 = 0; d0 < 128; d0 += 4) {
            const float4 w0 = *(const float4*)&W_trk2[(d0 + 0) * 128 + c0];
            const float4 w1 = *(const float4*)&W_trk2[(d0 + 1) * 128 + c0];
            const float4 w2 = *(const float4*)&W_trk2[(d0 + 2) * 128 + c0];
            const float4 w3 = *(const float4*)&W_trk2[(d0 + 3) * 128 + c0];
            #pragma unroll
            for (int i = 0; i < 4; i++) {
                const float4 h = *(const float4*)&sB[(r0 + i) * 128 + d0];
                FMA4(acc[i], h.x, w0); FMA4(acc[i], h.y, w1);
                FMA4(acc[i], h.z, w2); FMA4(acc[i], h.w, w3);
            }
        }
        #pragma unroll
        for (int i = 0; i < 4; i++) {
            float4 r;
            r.x = fmaxf(acc[i].x, 0.f); r.y = fmaxf(acc[i].y, 0.f);
            r.z = fmaxf(acc[i].z, 0.f); r.w = fmaxf(acc[i].w, 0.f);
            *(float4*)&sA[ROTV(r0 + i, c0)] = r;
        }
    }
    __syncthreads();
    {
        const float w0 = W_sv1[c128], w1 = W_sv1[128 + c128];
        const float b1 = b_sv1[c128];
        #pragma unroll
        for (int i = 0; i < 4; i++) {
            const int s = g4 * 4 + i;
            sB[s * 128 + c128] =
                elu_ref(fmaf(sC[2560 + s * 2 + 1], w1, fmaf(sC[2560 + s * 2], w0, b1)));
        }
    }
    __syncthreads();
    {
        const int s = rg;
        float4 acc = *(const float4*)&b_sv2[c0];
        for (int d0 = 0; d0 < 128; d0 += 4) {
            const float4 w0 = *(const float4*)&W_sv2[(d0 + 0) * 128 + c0];
            const float4 w1 = *(const float4*)&W_sv2[(d0 + 1) * 128 + c0];
            const float4 w2 = *(const float4*)&W_sv2[(d0 + 2) * 128 + c0];
            const float4 w3 = *(const float4*)&W_sv2[(d0 + 3) * 128 + c0];
            const float4 h = *(const float4*)&sB[s * 128 + d0];
            FMA4(acc, h.x, w0); FMA4(acc, h.y, w1);
            FMA4(acc, h.z, w2); FMA4(acc, h.w, w3);
        }
        float4 r;
        r.x = fmaxf(acc.x, 0.f); r.y = fmaxf(acc.y, 0.f);
        r.z = fmaxf(acc.z, 0.f); r.w = fmaxf(acc.w, 0.f);
        *(float4*)&sC[ROTV(s, c0)] = r;
    }
    __syncthreads();
    unsigned pack1;
    {
        {
            const int s = rg;
            float4 acc = {0.f, 0.f, 0.f, 0.f};
            for (int d0 = 0; d0 < 128; d0 += 4) {
                const float4 e  = *(const float4*)&sC[ROTV(s, d0)];
                const float4 w0 = *(const float4*)&W_c1[(128 + d0 + 0) * 128 + c0];
                const float4 w1 = *(const float4*)&W_c1[(128 + d0 + 1) * 128 + c0];
                const float4 w2 = *(const float4*)&W_c1[(128 + d0 + 2) * 128 + c0];
                const float4 w3 = *(const float4*)&W_c1[(128 + d0 + 3) * 128 + c0];
                FMA4(acc, e.x, w0); FMA4(acc, e.y, w1);
                FMA4(acc, e.z, w2); FMA4(acc, e.w, w3);
            }
            *(float4*)&sC[BS1V(s, c0)] = acc;
        }
        const int q  = tid >> 3;
        const int s0 = tid & 7;
        float d0a = 0.f, d1a = 0.f, n0 = 0.f, n1 = 0.f;
        for (int d0 = 0; d0 < 128; d0 += 4) {
            const float4 t  = *(const float4*)&sA[ROTV(q, d0)];
            const float4 v0 = *(const float4*)&sC[ROTV(s0, d0)];
            const float4 v1 = *(const float4*)&sC[ROTV(s0 + 8, d0)];
            d0a += t.x * v0.x + t.y * v0.y + t.z * v0.z + t.w * v0.w;
            d1a += t.x * v1.x + t.y * v1.y + t.z * v1.z + t.w * v1.w;
            n0  += v0.x * v0.x + v0.y * v0.y + v0.z * v0.z + v0.w * v0.w;
            n1  += v1.x * v1.x + v1.y * v1.y + v1.z * v1.z + v1.w * v1.w;
        }
        float sc0 = fmaf(-2.f, d0a, n0);
        float sc1 = fmaf(-2.f, d1a, n1);
        pack1 = 0u;
        #pragma unroll
        for (int r = 0; r < 8; r++) {
            float bv = sc0; int bs = s0;
            if (sc1 < bv) { bv = sc1; bs = s0 + 8; }
            #pragma unroll
            for (int o = 1; o <= 4; o <<= 1) {
                const float ov = __shfl_xor(bv, o, 8);
                const int   os = __shfl_xor(bs, o, 8);
                if (ov < bv || (ov == bv && os < bs)) { bv = ov; bs = os; }
            }
            pack1 |= (unsigned)bs << (4 * r);
            if (bs == s0)     sc0 = INF_F;
            if (bs == s0 + 8) sc1 = INF_F;
        }
    }
    __syncthreads();
    float4 a2v[4];
    {
        const int q0 = rg * 4;
        float4 a1[4];
        const float4 bc1 = *(const float4*)&b_c1[c0];
        const float4 bc2 = *(const float4*)&b_c2[c0];
        #pragma unroll
        for (int i = 0; i < 4; i++) { a1[i] = bc1; a2v[i] = bc2; }
        for (int d0 = 0; d0 < 128; d0 += 4) {
            float4 t[4];
            #pragma unroll
            for (int i = 0; i < 4; i++) t[i] = *(const float4*)&sA[ROTV(q0 + i, d0)];
            #pragma unroll
            for (int dj = 0; dj < 4; dj++) {
                float4 wv;
                const float4 wa = *(const float4*)&W_c1[(d0 + dj) * 128 + c0];
                const float4 wb = *(const float4*)&W_c1[(128 + d0 + dj) * 128 + c0];
                wv.x = wa.x - wb.x; wv.y = wa.y - wb.y;
                wv.z = wa.z - wb.z; wv.w = wa.w - wb.w;
                FMA4(a1[0], ((const float*)&t[0])[dj], wv);
                FMA4(a1[1], ((const float*)&t[1])[dj], wv);
                FMA4(a1[2], ((const float*)&t[2])[dj], wv);
                FMA4(a1[3], ((const float*)&t[3])[dj], wv);
            }
            #pragma unroll
            for (int dj = 0; dj < 4; dj++) {
                float4 wv;
                const float4 wa = *(const float4*)&W_c2[(d0 + dj) * 128 + c0];
                const float4 wb = *(const float4*)&W_c2[(128 + d0 + dj) * 128 + c0];
                wv.x = wa.x - wb.x; wv.y = wa.y - wb.y;
                wv.z = wa.z - wb.z; wv.w = wa.w - wb.w;
                FMA4(a2v[0], ((const float*)&t[0])[dj], wv);
                FMA4(a2v[1], ((const float*)&t[1])[dj], wv);
                FMA4(a2v[2], ((const float*)&t[2])[dj], wv);
                FMA4(a2v[3], ((const float*)&t[3])[dj], wv);
            }
        }
        #pragma unroll
        for (int i = 0; i < 4; i++) {
            const int q = q0 + i;
            const unsigned pk = __shfl(pack1, 8 * i + lane_hi);
            float4 m = {-INF_F, -INF_F, -INF_F, -INF_F};
            #pragma unroll
            for (int j = 0; j < 8; j++) {
                const int s = (int)((pk >> (4 * j)) & 15u);
                const float4 b = *(const float4*)&sC[BS1V(s, c0)];
                MAX4(m, b);
            }
            float4 f;
            f.x = elu_ref(a1[i].x + m.x); f.y = elu_ref(a1[i].y + m.y);
            f.z = elu_ref(a1[i].z + m.z); f.w = elu_ref(a1[i].w + m.w);
            *(float4*)&sB[ROTV(q, c0)] = f;
        }
    }
    __syncthreads();
    {
        const int s  = tid & 63;
        const int q0 = (tid >> 6) * 8;
        float acc[8];
        #pragma unroll
        for (int i = 0; i < 8; i++) acc[i] = 0.f;
        float nrm = 0.f;
        for (int d0 = 0; d0 < 128; d0 += 4) {
            const float4 f = *(const float4*)&sB[ROTV(s, d0)];
            nrm = fmaf(f.x, f.x, nrm); nrm = fmaf(f.y, f.y, nrm);
            nrm = fmaf(f.z, f.z, nrm); nrm = fmaf(f.w, f.w, nrm);
            #pragma unroll
            for (int i = 0; i < 8; i++) {
                const float4 t = *(const float4*)&sA[ROTV(q0 + i, d0)];
                acc[i] = fmaf(t.x, f.x, acc[i]); acc[i] = fmaf(t.y, f.y, acc[i]);
                acc[i] = fmaf(t.z, f.z, acc[i]); acc[i] = fmaf(t.w, f.w, acc[i]);
            }
        }
        #pragma unroll
        for (int i = 0; i < 8; i++)
            sC[(q0 + i) * 64 + s] = fmaf(-2.f, acc[i], nrm);
    }
    __syncthreads();
    unsigned lo2, hi2;
    {
        const int q = tid >> 3;
        const int j = tid & 7;
        float v[8];
        *(float4*)&v[0] = *(const float4*)&sC[q * 64 + 8 * j];
        *(float4*)&v[4] = *(const float4*)&sC[q * 64 + 8 * j + 4];
        lo2 = 0u; hi2 = 0u;
        #pragma unroll
        for (int r = 0; r < 8; r++) {
            float bv = v[0]; int bs = 8 * j;
            #pragma unroll
            for (int t = 1; t < 8; t++)
                if (v[t] < bv) { bv = v[t]; bs = 8 * j + t; }
            #pragma unroll
            for (int o = 1; o <= 4; o <<= 1) {
                const float ov = __shfl_xor(bv, o, 8);
                const int   os = __shfl_xor(bs, o, 8);
                if (ov < bv || (ov == bv && os < bs)) { bv = ov; bs = os; }
            }
            if (r < 4) lo2 |= (unsigned)bs << (8 * r);
            else       hi2 |= (unsigned)bs << (8 * (r - 4));
            #pragma unroll
            for (int t = 0; t < 8; t++)
                if (bs == 8 * j + t) v[t] = INF_F;
        }
        const int r0 = rg * 4;
        float4 acc[4];
        #pragma unroll
        for (int i = 0; i < 4; i++) acc[i] = make_float4(0.f, 0.f, 0.f, 0.f);
        for (int d0 = 0; d0 < 128; d0 += 4) {
            const float4 w0 = *(const float4*)&W_c2[(128 + d0 + 0) * 128 + c0];
            const float4 w1 = *(const float4*)&W_c2[(128 + d0 + 1) * 128 + c0];
            const float4 w2 = *(const float4*)&W_c2[(128 + d0 + 2) * 128 + c0];
            const float4 w3 = *(const float4*)&W_c2[(128 + d0 + 3) * 128 + c0];
            #pragma unroll
            for (int i = 0; i < 4; i++) {
                const float4 f = *(const float4*)&sB[ROTV(r0 + i, d0)];
                FMA4(acc[i], f.x, w0); FMA4(acc[i], f.y, w1);
                FMA4(acc[i], f.z, w2); FMA4(acc[i], f.w, w3);
            }
        }
        #pragma unroll
        for (int i = 0; i < 4; i++)
            *(float4*)&sA[ROTV(r0 + i, c0)] = acc[i];
    }
    __syncthreads();
    {
        const int q0 = rg * 4;
        float4 ps = {0.f, 0.f, 0.f, 0.f};
        #pragma unroll
        for (int i = 0; i < 4; i++) {
            const unsigned plo = __shfl(lo2, 8 * i + lane_hi);
            const unsigned phi = __shfl(hi2, 8 * i + lane_hi);
            float4 m = {-INF_F, -INF_F, -INF_F, -INF_F};
            #pragma unroll
            for (int j = 0; j < 8; j++) {
                const int s = (int)(((j < 4) ? (plo >> (8 * j)) : (phi >> (8 * (j - 4)))) & 63u);
                const float4 b = *(const float4*)&sA[ROTV(s, c0)];
                MAX4(m, b);
            }
            ps.x += elu_ref(a2v[i].x + m.x); ps.y += elu_ref(a2v[i].y + m.y);
            ps.z += elu_ref(a2v[i].z + m.z); ps.w += elu_ref(a2v[i].w + m.w);
        }
        *(float4*)&sB[rg * 128 + c0] = ps;
    }
    __syncthreads();
    if (tid < 128) {
        float p = 0.f;
        #pragma unroll
        for (int t = 0; t < 16; t++) p += sB[t * 128 + tid];
        sB[2048 + tid] = p * (1.f / 64.f);
    }
    __syncthreads();
    if (tid < 64) {
        float acc = b_o1[tid];
        for (int d = 0; d < 128; d++) acc = fmaf(sB[2048 + d], W_o1[d * 64 + tid], acc);
        sB[2176 + tid] = elu_ref(acc);
    }
    __syncthreads();
    if (tid < 32) {
        float acc = b_o2[tid];
        for (int d = 0; d < 64; d++) acc = fmaf(sB[2176 + d], W_o2[d * 32 + tid], acc);
        sB[2240 + tid] = elu_ref(acc);
    }
    __syncthreads();
    if (tid < 4) {
        float acc = b_o3[tid];
        for (int d = 0; d < 32; d++) acc = fmaf(sB[2240 + d], W_o3[d * 4 + tid], acc);
        sB[2272 + tid] = elu_ref(acc);
    }
    __syncthreads();
    if (tid == 0) {
        float acc = b_o4[0];
        #pragma unroll
        for (int d = 0; d < 4; d++) acc = fmaf(sB[2272 + d], W_o4[d], acc);
        out[g] = acc;
        out[G_ + g] = (float)g;
    }
}

extern "C" void kernel_launch(void* const* d_in, const int* in_sizes, int n_in,
                              void* d_out, int out_size, void* d_ws, size_t ws_size,
                              hipStream_t stream) {
    const float* x_sv   = (const float*)d_in[0];
    const float* x_trk  = (const float*)d_in[1];
    const float* W_sv1  = (const float*)d_in[2];
    const float* b_sv1  = (const float*)d_in[3];
    const float* W_sv2  = (const float*)d_in[4];
    const float* b_sv2  = (const float*)d_in[5];
    const float* W_trk1 = (const float*)d_in[6];
    const float* b_trk1 = (const float*)d_in[7];
    const float* W_trk2 = (const float*)d_in[8];
    const float* b_trk2 = (const float*)d_in[9];
    const float* W_c1   = (const float*)d_in[10];
    const float* b_c1   = (const float*)d_in[11];
    const float* W_c2   = (const float*)d_in[12];
    const float* b_c2   = (const float*)d_in[13];
    const float* W_o1   = (const float*)d_in[14];
    const float* b_o1   = (const float*)d_in[15];
    const float* W_o2   = (const float*)d_in[16];
    const float* b_o2   = (const float*)d_in[17];
    const float* W_o3   = (const float*)d_in[18];
    const float* b_o3   = (const float*)d_in[19];
    const float* W_o4   = (const float*)d_in[20];
    const float* b_o4   = (const float*)d_in[21];
    float* out = (float*)d_out;

    const size_t WS_NEED = (size_t)6 * 16384 * sizeof(unsigned short); // 192 KB
    if (ws_size >= WS_NEED && d_ws != nullptr) {
        unsigned short* wsu = (unsigned short*)d_ws;
        prep_pack<<<384, 256, 0, stream>>>(W_trk2, W_sv2, W_c1, W_c2, wsu);
        fused_mfma<<<G_, TPB, 0, stream>>>(x_sv, x_trk, W_sv1, b_sv1, b_sv2,
                                           W_trk1, b_trk1, b_trk2, b_c1, b_c2,
                                           W_o1, b_o1, W_o2, b_o2, W_o3, b_o3,
                                           W_o4, b_o4, wsu, out);
    } else {
        fused_vec<<<G_, TPB, 0, stream>>>(x_sv, x_trk, W_sv1, b_sv1, W_sv2, b_sv2,
                                          W_trk1, b_trk1, W_trk2, b_trk2,
                                          W_c1, b_c1, W_c2, b_c2,
                                          W_o1, b_o1, W_o2, b_o2, W_o3, b_o3,
                                          W_o4, b_o4, out);
    }
}